// Round 6
// baseline (197.310 us; speedup 1.0000x reference)
//
#include <hip/hip_runtime.h>

// Correlation layer, two-pass banded-MFMA with LDS-DMA pipeline (gfx950).
// out[b, dy*9+dx, y, x] = sum_c f1[b,c,y,x] * f2[b,c,y+dy-4,x+dx-4]
//
// R15: attack the barrier skeleton (R14 falsified the f1-latency theory:
// deeper f1 prefetch + setprio + fences all null at 53.5us; throughput
// floors sum to ~12us, so the 4x gap is the 2-barrier-per-chunk lockstep).
//  1. dy-split across blocks: block computes dy 0..4 or 5..8 -> 12-row
//     staged tile (24KB), acc 40 VGPR, grid 1024 = EXACTLY 2 rounds of 512
//     at 2 blocks/CU. Disjoint outputs, no extra write traffic.
//  2. triple-buffered LDS (3x24KB=72KB) -> ONE barrier per chunk: with 3
//     buffers, stage(ch+2) targets the buffer whose readers (chunk ch-1)
//     finished before this chunk's barrier -> the WAR barrier is deleted.
//     Counted vmcnt(3) keeps stage(ch+1) in flight; vmcnt(0) only at ch=7.
//  3. f1 hoisted fully into prologue: af8[8] packed A-fragments (32 VGPR);
//     the chunk loop is pure {vmcnt, barrier, stage-issue, MFMA}.
// OOB guard: (yg=7,half=1,r=11) would read w2 row 72 -> clamp source row to
// 71 (garbage lands in unread LDS row 11; instr count stays wave-uniform so
// vmcnt accounting holds for every wave).
// Kept from R13/R14 (verified): XOR swizzle both-sides (0 bank conflicts),
// b=id&7 XCD pin, fragment-ready w2 layout, float2-vectorized cvt, banded
// 2-tile epilogue writing each output exactly once.

namespace {
constexpr int B_ = 8, C_ = 256, H_ = 64, W_ = 128;
constexpr int SIDE = 9, ND = 81, PAD = 4;
constexpr int HW = H_ * W_;
constexpr int KC = 32, NCH = C_ / KC;       // 8 chunks of 32 channels
constexpr int YB = 8, XB = 16;
constexpr int NQ = 4;                       // channel-octs per chunk
constexpr int YP_ = H_ + 2 * PAD;           // 72
constexpr int XP_ = 144;                    // padded x (x+4)
constexpr size_t ROWU = (size_t)NQ * XP_;   // 576 uint4 per (b,cs,yp)
constexpr size_t PERB = (size_t)NCH * YP_ * ROWU;  // 331,776
constexpr size_t NW2 = (size_t)B_ * PERB;          // 2,654,208 uint4
constexpr size_t WS_BYTES = NW2 * 16;              // 42.5 MB
constexpr int RSTG = 12;                           // staged rows per dy-half
constexpr int TILE_U4 = RSTG * NQ * 32;            // 1536 uint4 = 24 KB
}

typedef __attribute__((ext_vector_type(8))) short short8;
typedef __attribute__((ext_vector_type(4))) float float4v;
typedef __attribute__((address_space(1))) void gvoid;
typedef __attribute__((address_space(3))) void svoid;

__device__ __forceinline__ unsigned bf16rne(float f) {
  unsigned u = __float_as_uint(f);
  return (u + 0x7fffu + ((u >> 16) & 1u)) >> 16;
}
__device__ __forceinline__ unsigned packbf2(float lo, float hi) {
  return bf16rne(lo) | (bf16rne(hi) << 16);
}

// ------- pass 1: f2 fp32 -> fragment-ready bf16 w2, XCD-swizzled -------
// Each thread produces TWO consecutive uint4 (x pair) via float2 loads.
__global__ __launch_bounds__(256)
void cvt_f2(const float* __restrict__ f2, uint4* __restrict__ w2) {
  const int id = blockIdx.x;
  const int b = id & 7;                              // XCD pin
  const int e2 = (id >> 3) * 256 + (int)threadIdx.x; // pair idx
  const int xp2 = e2 % (XP_ / 2);
  int r = e2 / (XP_ / 2);
  const int q = r & 3;
  r >>= 2;
  const int yp = r % YP_;
  const int cs = r / YP_;
  const int xp = 2 * xp2;
  const int yg = yp - PAD, xg = xp - PAD;            // xg even
  uint4 o0 = {0u, 0u, 0u, 0u}, o1 = o0;
  if (yg >= 0 && yg < H_ && xg >= 0 && xg <= W_ - 2) {
    const float* s =
        f2 + ((size_t)(b * C_ + cs * KC + q * 8) * H_ + yg) * W_ + xg;
    const float2 v0 = *(const float2*)(s + 0 * HW);
    const float2 v1 = *(const float2*)(s + 1 * HW);
    const float2 v2 = *(const float2*)(s + 2 * HW);
    const float2 v3 = *(const float2*)(s + 3 * HW);
    const float2 v4 = *(const float2*)(s + 4 * HW);
    const float2 v5 = *(const float2*)(s + 5 * HW);
    const float2 v6 = *(const float2*)(s + 6 * HW);
    const float2 v7 = *(const float2*)(s + 7 * HW);
    o0.x = packbf2(v0.x, v1.x);  o1.x = packbf2(v0.y, v1.y);
    o0.y = packbf2(v2.x, v3.x);  o1.y = packbf2(v2.y, v3.y);
    o0.z = packbf2(v4.x, v5.x);  o1.z = packbf2(v4.y, v5.y);
    o0.w = packbf2(v6.x, v7.x);  o1.w = packbf2(v6.y, v7.y);
  }
  const size_t e = (((size_t)(cs * YP_ + yp) * NQ + q) * XP_) + xp;
  uint4* d = w2 + (size_t)b * PERB + e;
  d[0] = o0;
  d[1] = o1;
}

// ------- pass 2: banded MFMA, dy-split, 3-buffer 1-barrier pipeline -------
__global__ __launch_bounds__(512, 4)
void corr_mfma3(const float* __restrict__ f1, const uint4* __restrict__ w2,
                float* __restrict__ out) {
  __shared__ uint4 f2s[3 * TILE_U4];             // 72 KB, three 24 KB buffers

  const int id = blockIdx.x;
  const int b = id & 7;                          // XCD pin (matches cvt)
  const int k = id >> 3;                         // 0..127
  const int xg = k & 7;                          // x fast: neighbors share rows
  const int half = (k >> 3) & 1;                 // dy half: 0->0..4, 1->5..8
  const int yg = k >> 4;                         // 0..7
  const int x0 = xg * XB, y0 = yg * YB;
  const int y0r = y0 + 5 * half;                 // staged row base (yp-space)
  const int ndy = 5 - half;

  const int t = threadIdx.x, lane = t & 63, w = t >> 6;  // wave -> row y0+w
  const int v = lane & 15, q = lane >> 4;
  const int sq = q << 1;                         // read-side XOR swizzle
  const int l_hi = lane >> 5;                    // staging lane geometry
  const int l_xq = lane & 31;

  const uint4* w2b = w2 + (size_t)b * PERB;
  const float* f1b = f1 + (size_t)b * C_ * HW;

  // 3 global_load_lds per wave per chunk: g=w*3+kk covers (row r=g>>1,
  // oct-pair qp=g&1) over 12 rows x 4 octs. Lane -> oct qq=2qp+(lane>>5),
  // col slot xq=lane&31, source col x0+(xq^(qq<<1)) (pre-swizzled global,
  // linear LDS dest). Source row clamped to YP_-1 (OOB guard, count-uniform).
  auto issue_stage = [&](int ch, int buf) {
    const uint4* wc = w2b + (size_t)ch * ((size_t)YP_ * ROWU);
#pragma unroll
    for (int kk = 0; kk < 3; ++kk) {
      const int g = w * 3 + kk;
      const int r = g >> 1, qp = g & 1;
      int rs = y0r + r;
      rs = rs > YP_ - 1 ? YP_ - 1 : rs;
      const int qq = 2 * qp + l_hi;
      const int xqs = l_xq ^ (qq << 1);
      const uint4* gp = wc + (size_t)rs * ROWU + (size_t)qq * XP_ + x0 + xqs;
      uint4* lp = &f2s[buf * TILE_U4 + (r * NQ + qp * 2) * 32];
      __builtin_amdgcn_global_load_lds((gvoid*)gp, (svoid*)lp, 16, 0, 0);
    }
  };

  // ---- prologue: pack ALL f1 A-fragments into registers (32 VGPR) ----
  uint4 af8[NCH];
  {
    const float* fb = f1b + ((size_t)(q * 8) * H_ + (y0 + w)) * W_ + x0 + v;
    float ta[8], tb[8];
#pragma unroll
    for (int j = 0; j < 8; ++j) ta[j] = fb[(size_t)j * HW];
#pragma unroll
    for (int c = 0; c < NCH; ++c) {
      float* cur = (c & 1) ? tb : ta;
      float* nxt = (c & 1) ? ta : tb;
      if (c + 1 < NCH) {
#pragma unroll
        for (int j = 0; j < 8; ++j)
          nxt[j] = fb[(size_t)((c + 1) * KC + j) * HW];
      }
      uint4 u;
      u.x = packbf2(cur[0], cur[1]);
      u.y = packbf2(cur[2], cur[3]);
      u.z = packbf2(cur[4], cur[5]);
      u.w = packbf2(cur[6], cur[7]);
      af8[c] = u;
    }
  }

  float4v acc[5][2];
#pragma unroll
  for (int i = 0; i < 5; ++i) {
    acc[i][0] = (float4v){0.f, 0.f, 0.f, 0.f};
    acc[i][1] = (float4v){0.f, 0.f, 0.f, 0.f};
  }

  issue_stage(0, 0);
  issue_stage(1, 1);
  __builtin_amdgcn_sched_barrier(0);

#pragma unroll
  for (int ch = 0; ch < NCH; ++ch) {
    // Outstanding here: [stage(ch):3, stage(ch+1):3]. vmcnt(3) drains
    // stage(ch), keeps stage(ch+1) in flight. Final chunk must drain fully.
    if (ch == NCH - 1)
      asm volatile("s_waitcnt vmcnt(0)" ::: "memory");
    else
      asm volatile("s_waitcnt vmcnt(3)" ::: "memory");
    __builtin_amdgcn_sched_barrier(0);
    __builtin_amdgcn_s_barrier();                // single barrier per chunk
    __builtin_amdgcn_sched_barrier(0);

    // stage(ch+2) -> buf (ch+2)%3 = (ch-1)%3: its readers (chunk ch-1's
    // MFMAs) consumed their LDS data before reaching this barrier. Safe.
    if (ch + 2 < NCH) issue_stage(ch + 2, (ch + 2) % 3);
    __builtin_amdgcn_sched_barrier(0);

    const int bo = (ch % 3) * TILE_U4;
    const short8 af = __builtin_bit_cast(short8, af8[ch]);
    __builtin_amdgcn_s_setprio(1);
#pragma unroll
    for (int i = 0; i < 5; ++i) {
      if (i < ndy) {
        const uint4* base = &f2s[bo + ((w + i) * NQ + q) * 32];
        const short8 b0 = __builtin_bit_cast(short8, base[v ^ sq]);
        const short8 b1 = __builtin_bit_cast(short8, base[(v + 16) ^ sq]);
        acc[i][0] = __builtin_amdgcn_mfma_f32_16x16x32_bf16(af, b0, acc[i][0],
                                                            0, 0, 0);
        acc[i][1] = __builtin_amdgcn_mfma_f32_16x16x32_bf16(af, b1, acc[i][1],
                                                            0, 0, 0);
      }
    }
    __builtin_amdgcn_s_setprio(0);
    __builtin_amdgcn_sched_barrier(0);
  }

  // Epilogue: C/D col n = v, row m = q*4+r. tile0: dx = v-m in [0,8];
  // tile1: dx = v-m+16 in [1,8]. Each output element written exactly once.
  const int y = y0 + w;
  float* outb = out + (size_t)b * ND * HW + (size_t)y * W_ + x0;
#pragma unroll
  for (int i = 0; i < 5; ++i) {
    if (i < ndy) {
      const int dyg = half * 5 + i;
#pragma unroll
      for (int r = 0; r < 4; ++r) {
        const int m = q * 4 + r;
        const int dx0 = v - m;
        if (dx0 >= 0 && dx0 <= 8)
          outb[(size_t)(dyg * SIDE + dx0) * HW + m] = acc[i][0][r];
        const int dx1 = v - m + 16;
        if (dx1 <= 8)
          outb[(size_t)(dyg * SIDE + dx1) * HW + m] = acc[i][1][r];
      }
    }
  }
}

// ---------------- fallback (R10 fused kernel, proven) if ws too small ------
namespace fb {
constexpr int PXS = 20, F2PX = 32, RWS = 16, F2U = RWS * (F2PX / 4) * 16;
}

__global__ __launch_bounds__(512, 4)
void corr_fb(const float* __restrict__ f1, const float* __restrict__ f2,
             float* __restrict__ out) {
  using namespace fb;
  __shared__ __align__(16) unsigned f2s[RWS * F2PX * PXS];
  __shared__ __align__(16) unsigned f1s[YB * XB * PXS];

  const int id = blockIdx.x;
  const int b = id & 7;
  const int k = id >> 3;
  const int xg = k & 7, yg = k >> 3;
  const int x0 = xg * XB, y0 = yg * YB;
  const int t = threadIdx.x, lane = t & 63, w = t >> 6;
  const int v = lane & 15, q = lane >> 4;

  float4v acc[SIDE][2];
#pragma unroll
  for (int i = 0; i < SIDE; ++i) {
    acc[i][0] = (float4v){0.f, 0.f, 0.f, 0.f};
    acc[i][1] = (float4v){0.f, 0.f, 0.f, 0.f};
  }
  const float* __restrict__ f1b = f1 + (size_t)b * C_ * HW;
  const float* __restrict__ f2b = f2 + (size_t)b * C_ * HW;

  for (int ch = 0; ch < NCH; ++ch) {
    const int c0 = ch * KC;
    if (ch) __syncthreads();
#pragma unroll
    for (int u0 = 0; u0 < F2U; u0 += 512) {
      const int u = u0 + t;
      const int cp = u & 15;
      const int t2 = u >> 4;
      const int pxq = t2 & 7;
      const int r = t2 >> 3;
      const int ygl = y0 - PAD + r;
      const int xb = x0 - PAD + pxq * 4;
      float4 va = make_float4(0.f, 0.f, 0.f, 0.f), vb = va;
      if (ygl >= 0 && ygl < H_ && xb >= 0 && xb <= W_ - 4) {
        const float* p = f2b + ((size_t)(c0 + 2 * cp) * H_ + ygl) * W_ + xb;
        va = *(const float4*)p;
        vb = *(const float4*)(p + HW);
      }
      unsigned* d = &f2s[(r * F2PX + pxq * 4) * PXS + cp];
      d[0 * PXS] = packbf2(va.x, vb.x);
      d[1 * PXS] = packbf2(va.y, vb.y);
      d[2 * PXS] = packbf2(va.z, vb.z);
      d[3 * PXS] = packbf2(va.w, vb.w);
    }
    {
      const int cp = t & 15;
      const int t2 = t >> 4;
      const int pxq = t2 & 3;
      const int r = t2 >> 2;
      const float* p =
          f1b + ((size_t)(c0 + 2 * cp) * H_ + (y0 + r)) * W_ + x0 + pxq * 4;
      const float4 va = *(const float4*)p;
      const float4 vb = *(const float4*)(p + HW);
      unsigned* d = &f1s[(r * XB + pxq * 4) * PXS + cp];
      d[0 * PXS] = packbf2(va.x, vb.x);
      d[1 * PXS] = packbf2(va.y, vb.y);
      d[2 * PXS] = packbf2(va.z, vb.z);
      d[3 * PXS] = packbf2(va.w, vb.w);
    }
    __syncthreads();

    const short8 af = __builtin_bit_cast(
        short8, *(const uint4*)&f1s[(w * XB + v) * PXS + 4 * q]);
#pragma unroll
    for (int dy = 0; dy < SIDE; ++dy) {
      const unsigned* fp = &f2s[((w + dy) * F2PX + v) * PXS + 4 * q];
      const short8 b0 = __builtin_bit_cast(short8, *(const uint4*)fp);
      const short8 b1 =
          __builtin_bit_cast(short8, *(const uint4*)(fp + 16 * PXS));
      acc[dy][0] =
          __builtin_amdgcn_mfma_f32_16x16x32_bf16(af, b0, acc[dy][0], 0, 0, 0);
      acc[dy][1] =
          __builtin_amdgcn_mfma_f32_16x16x32_bf16(af, b1, acc[dy][1], 0, 0, 0);
    }
  }
  const int y = y0 + w;
  float* outb = out + (size_t)b * ND * HW + (size_t)y * W_ + x0;
#pragma unroll
  for (int dy = 0; dy < SIDE; ++dy) {
#pragma unroll
    for (int r = 0; r < 4; ++r) {
      const int m = q * 4 + r;
      const int dx0 = v - m;
      if (dx0 >= 0 && dx0 <= 8)
        outb[(size_t)(dy * SIDE + dx0) * HW + m] = acc[dy][0][r];
      const int dx1 = v - m + 16;
      if (dx1 <= 8)
        outb[(size_t)(dy * SIDE + dx1) * HW + m] = acc[dy][1][r];
    }
  }
}

extern "C" void kernel_launch(void* const* d_in, const int* in_sizes, int n_in,
                              void* d_out, int out_size, void* d_ws,
                              size_t ws_size, hipStream_t stream) {
  (void)in_sizes; (void)n_in; (void)out_size;
  const float* f1 = (const float*)d_in[0];
  const float* f2 = (const float*)d_in[1];
  float* out = (float*)d_out;
  if (ws_size >= WS_BYTES) {
    uint4* w2 = (uint4*)d_ws;
    cvt_f2<<<dim3((unsigned)(NW2 / 512)), 256, 0, stream>>>(f2, w2);
    corr_mfma3<<<dim3(1024), 512, 0, stream>>>(f1, w2, out);
  } else {
    corr_fb<<<dim3(512), 512, 0, stream>>>(f1, f2, out);
  }
}

// Round 7
// 193.378 us; speedup vs baseline: 1.0203x; 1.0203x over previous
//
#include <hip/hip_runtime.h>

// Correlation layer, two-pass banded-MFMA with LDS-DMA pipeline (gfx950).
// out[b, dy*9+dx, y, x] = sum_c f1[b,c,y,x] * f2[b,c,y+dy-4,x+dx-4]
//
// R16: occupancy-first re-tile of the proven R13 skeleton.
// Diagnosis: gfx950 unified VGPR+AGPR file -> R13 was 64 VGPR + 80 AGPR
// = 144/wave -> ONE 512-thr block per CU = 8 waves/CU (25%), 2 grid rounds.
// All-pipes-idle counters = latency starvation, not BW (no pipe >25%).
// Fix: 256-thr blocks (4 waves = 1 wave/SIMD, no quantization cliff),
// dy-split (acc 40 AGPR), f1 via 2-deep reg double-buffer (16 VGPR, no af8
// hoist), __launch_bounds__(256,5) -> ~90-100 unified regs -> 5 blocks/CU
// = 20 waves/CU, LDS 5 x 32KB = 160KB exact.
//  - block = 4 y-rows x 16 px x one dy-half (5 or 4 dy); staged tile
//    8 rows x 4 octs x 32 slots = 16 KB, double-buffered (32 KB).
//  - grid 2048 = 8b x 8xg x 2half x 16ygq, b=id&7 XCD pin, xg fastest.
//  - chunk skeleton IDENTICAL to R13 (proven): pack -> vmcnt(4) ->
//    s_barrier -> f1(ch+1) -> MFMA -> s_barrier -> stage(ch+2).
//    Per-wave FIFO [S(ch):4, f1(ch):8, S(ch+1):4]; vmcnt(4) keeps S(ch+1)
//    in flight, never drains to 0 mid-loop.
//  - XOR swizzle both-sides (R13-verified: 0 bank conflicts).
//  - OOB guard: half1 stages row y0+12 (unused) -> clamp yp<=71,
//    count-uniform so vmcnt accounting holds.
// cvt_f2 unchanged (R14 float2 version).

namespace {
constexpr int B_ = 8, C_ = 256, H_ = 64, W_ = 128;
constexpr int SIDE = 9, ND = 81, PAD = 4;
constexpr int HW = H_ * W_;
constexpr int KC = 32, NCH = C_ / KC;       // 8 chunks of 32 channels
constexpr int YB = 4, XB = 16;              // per-block output tile
constexpr int NQ = 4;                       // channel-octs per chunk
constexpr int YP_ = H_ + 2 * PAD;           // 72
constexpr int XP_ = 144;                    // padded x (x+4)
constexpr size_t ROWU = (size_t)NQ * XP_;   // 576 uint4 per (b,cs,yp)
constexpr size_t PERB = (size_t)NCH * YP_ * ROWU;  // 331,776
constexpr size_t NW2 = (size_t)B_ * PERB;          // 2,654,208 uint4
constexpr size_t WS_BYTES = NW2 * 16;              // 42.5 MB
constexpr int RSTG = 8;                            // staged rows per block
constexpr int TILE_U4 = RSTG * NQ * 32;            // 1024 uint4 = 16 KB
}

typedef __attribute__((ext_vector_type(8))) short short8;
typedef __attribute__((ext_vector_type(4))) float float4v;
typedef __attribute__((address_space(1))) void gvoid;
typedef __attribute__((address_space(3))) void svoid;

__device__ __forceinline__ unsigned bf16rne(float f) {
  unsigned u = __float_as_uint(f);
  return (u + 0x7fffu + ((u >> 16) & 1u)) >> 16;
}
__device__ __forceinline__ unsigned packbf2(float lo, float hi) {
  return bf16rne(lo) | (bf16rne(hi) << 16);
}

// ------- pass 1: f2 fp32 -> fragment-ready bf16 w2, XCD-swizzled -------
__global__ __launch_bounds__(256)
void cvt_f2(const float* __restrict__ f2, uint4* __restrict__ w2) {
  const int id = blockIdx.x;
  const int b = id & 7;                              // XCD pin
  const int e2 = (id >> 3) * 256 + (int)threadIdx.x; // pair idx
  const int xp2 = e2 % (XP_ / 2);
  int r = e2 / (XP_ / 2);
  const int q = r & 3;
  r >>= 2;
  const int yp = r % YP_;
  const int cs = r / YP_;
  const int xp = 2 * xp2;
  const int yg = yp - PAD, xg = xp - PAD;            // xg even
  uint4 o0 = {0u, 0u, 0u, 0u}, o1 = o0;
  if (yg >= 0 && yg < H_ && xg >= 0 && xg <= W_ - 2) {
    const float* s =
        f2 + ((size_t)(b * C_ + cs * KC + q * 8) * H_ + yg) * W_ + xg;
    const float2 v0 = *(const float2*)(s + 0 * HW);
    const float2 v1 = *(const float2*)(s + 1 * HW);
    const float2 v2 = *(const float2*)(s + 2 * HW);
    const float2 v3 = *(const float2*)(s + 3 * HW);
    const float2 v4 = *(const float2*)(s + 4 * HW);
    const float2 v5 = *(const float2*)(s + 5 * HW);
    const float2 v6 = *(const float2*)(s + 6 * HW);
    const float2 v7 = *(const float2*)(s + 7 * HW);
    o0.x = packbf2(v0.x, v1.x);  o1.x = packbf2(v0.y, v1.y);
    o0.y = packbf2(v2.x, v3.x);  o1.y = packbf2(v2.y, v3.y);
    o0.z = packbf2(v4.x, v5.x);  o1.z = packbf2(v4.y, v5.y);
    o0.w = packbf2(v6.x, v7.x);  o1.w = packbf2(v6.y, v7.y);
  }
  const size_t e = (((size_t)(cs * YP_ + yp) * NQ + q) * XP_) + xp;
  uint4* d = w2 + (size_t)b * PERB + e;
  d[0] = o0;
  d[1] = o1;
}

// ------- pass 2: banded MFMA, 256-thr dy-split, 5 blocks/CU -------
__global__ __launch_bounds__(256, 5)
void corr_mfma4(const float* __restrict__ f1, const uint4* __restrict__ w2,
                float* __restrict__ out) {
  __shared__ uint4 f2s[2 * TILE_U4];             // 32 KB, two 16 KB buffers

  const int id = blockIdx.x;
  const int b = id & 7;                          // XCD pin (matches cvt)
  const int t2 = id >> 3;
  const int xg = t2 & 7;                         // fastest: share halo rows
  const int t3 = t2 >> 3;
  const int half = t3 & 1;                       // dy half: 0->0..4, 1->5..8
  const int ygq = t3 >> 1;                       // 0..15
  const int x0 = xg * XB, y0 = ygq * YB;
  const int y0r = y0 + 5 * half;                 // staged row 0 in yp-space
  const int ndy = 5 - half;

  const int t = threadIdx.x, lane = t & 63, w = t >> 6;  // wave 0..3
  const int v = lane & 15, q = lane >> 4;
  const int sq = q << 1;                         // read-side XOR swizzle
  const int l_hi = lane >> 5;                    // staging lane geometry
  const int l_xq = lane & 31;

  const uint4* w2b = w2 + (size_t)b * PERB;
  const float* f1b = f1 + (size_t)b * C_ * HW;

  // 4 global_load_lds per wave per chunk: instr kk covers row r=2w+(kk>>1),
  // oct-pair qp=kk&1; lane -> oct qq=2qp+(lane>>5), slot xq=lane&31, source
  // col x0+(xq^(qq<<1)) (pre-swizzled global, linear LDS dest).
  auto issue_stage = [&](int ch, int buf) {
    const uint4* wc = w2b + (size_t)ch * ((size_t)YP_ * ROWU);
#pragma unroll
    for (int kk = 0; kk < 4; ++kk) {
      const int r = 2 * w + (kk >> 1);
      const int qp = kk & 1;
      int rs = y0r + r;
      rs = rs > YP_ - 1 ? YP_ - 1 : rs;          // OOB guard (unused row)
      const int qq = 2 * qp + l_hi;
      const int xqs = l_xq ^ (qq << 1);
      const uint4* gp = wc + (size_t)rs * ROWU + (size_t)qq * XP_ + x0 + xqs;
      uint4* lp = &f2s[buf * TILE_U4 + (r * NQ + qp * 2) * 32];
      __builtin_amdgcn_global_load_lds((gvoid*)gp, (svoid*)lp, 16, 0, 0);
    }
  };
  auto issue_f1 = [&](int ch, float* p) {
    const float* fp =
        f1b + ((size_t)(ch * KC + q * 8) * H_ + (y0 + w)) * W_ + x0 + v;
#pragma unroll
    for (int j = 0; j < 8; ++j) p[j] = fp[(size_t)j * HW];
  };

  float4v acc[5][2];
#pragma unroll
  for (int i = 0; i < 5; ++i) {
    acc[i][0] = (float4v){0.f, 0.f, 0.f, 0.f};
    acc[i][1] = (float4v){0.f, 0.f, 0.f, 0.f};
  }

  float p0[8], p1[8];
  issue_stage(0, 0);
  __builtin_amdgcn_sched_barrier(0);
  issue_f1(0, p0);
  __builtin_amdgcn_sched_barrier(0);
  issue_stage(1, 1);
  __builtin_amdgcn_sched_barrier(0);

#pragma unroll
  for (int ch = 0; ch < NCH; ++ch) {
    float* pc = (ch & 1) ? p1 : p0;              // ch literal under unroll
    uint4 afu;
    afu.x = packbf2(pc[0], pc[1]);
    afu.y = packbf2(pc[2], pc[3]);
    afu.z = packbf2(pc[4], pc[5]);
    afu.w = packbf2(pc[6], pc[7]);
    const short8 af = __builtin_bit_cast(short8, afu);

    // FIFO: [S(ch):4, f1(ch):8 (regs consumed), S(ch+1):4]. vmcnt(4)
    // drains S(ch)+f1(ch), keeps S(ch+1) in flight (never 0 mid-loop).
    asm volatile("s_waitcnt vmcnt(4)" ::: "memory");
    __builtin_amdgcn_sched_barrier(0);
    __builtin_amdgcn_s_barrier();
    __builtin_amdgcn_sched_barrier(0);

    if (ch + 1 < NCH) issue_f1(ch + 1, (ch & 1) ? p0 : p1);

    const int bo = (ch & 1) * TILE_U4;
    __builtin_amdgcn_s_setprio(1);
#pragma unroll
    for (int i = 0; i < 5; ++i) {
      if (i < ndy) {
        const uint4* base = &f2s[bo + ((w + i) * NQ + q) * 32];
        const short8 b0 = __builtin_bit_cast(short8, base[v ^ sq]);
        const short8 b1 = __builtin_bit_cast(short8, base[(v + 16) ^ sq]);
        acc[i][0] = __builtin_amdgcn_mfma_f32_16x16x32_bf16(af, b0, acc[i][0],
                                                            0, 0, 0);
        acc[i][1] = __builtin_amdgcn_mfma_f32_16x16x32_bf16(af, b1, acc[i][1],
                                                            0, 0, 0);
      }
    }
    __builtin_amdgcn_s_setprio(0);
    __builtin_amdgcn_sched_barrier(0);
    __builtin_amdgcn_s_barrier();                // all readers of buf done
    __builtin_amdgcn_sched_barrier(0);
    if (ch + 2 < NCH) issue_stage(ch + 2, ch & 1);  // overwrite after barrier
  }

  // Epilogue: C/D col n = v, row m = q*4+r. tile0: dx = v-m in [0,8];
  // tile1: dx = v-m+16 in [1,8]. Each output element written exactly once.
  const int y = y0 + w;
  float* outb = out + (size_t)b * ND * HW + (size_t)y * W_ + x0;
#pragma unroll
  for (int i = 0; i < 5; ++i) {
    if (i < ndy) {
      const int dyg = half * 5 + i;
#pragma unroll
      for (int r = 0; r < 4; ++r) {
        const int m = q * 4 + r;
        const int dx0 = v - m;
        if (dx0 >= 0 && dx0 <= 8)
          outb[(size_t)(dyg * SIDE + dx0) * HW + m] = acc[i][0][r];
        const int dx1 = v - m + 16;
        if (dx1 <= 8)
          outb[(size_t)(dyg * SIDE + dx1) * HW + m] = acc[i][1][r];
      }
    }
  }
}

// ---------------- fallback (R10 fused kernel, proven) if ws too small ------
namespace fb {
constexpr int PXS = 20, F2PX = 32, RWS = 16, F2U = RWS * (F2PX / 4) * 16;
constexpr int YBf = 8;
}

__global__ __launch_bounds__(512, 4)
void corr_fb(const float* __restrict__ f1, const float* __restrict__ f2,
             float* __restrict__ out) {
  using namespace fb;
  __shared__ __align__(16) unsigned f2s[RWS * F2PX * PXS];
  __shared__ __align__(16) unsigned f1s[YBf * XB * PXS];

  const int id = blockIdx.x;
  const int b = id & 7;
  const int k = id >> 3;
  const int xg = k & 7, yg = k >> 3;
  const int x0 = xg * XB, y0 = yg * YBf;
  const int t = threadIdx.x, lane = t & 63, w = t >> 6;
  const int v = lane & 15, q = lane >> 4;

  float4v acc[SIDE][2];
#pragma unroll
  for (int i = 0; i < SIDE; ++i) {
    acc[i][0] = (float4v){0.f, 0.f, 0.f, 0.f};
    acc[i][1] = (float4v){0.f, 0.f, 0.f, 0.f};
  }
  const float* __restrict__ f1b = f1 + (size_t)b * C_ * HW;
  const float* __restrict__ f2b = f2 + (size_t)b * C_ * HW;

  for (int ch = 0; ch < NCH; ++ch) {
    const int c0 = ch * KC;
    if (ch) __syncthreads();
#pragma unroll
    for (int u0 = 0; u0 < F2U; u0 += 512) {
      const int u = u0 + t;
      const int cp = u & 15;
      const int t2 = u >> 4;
      const int pxq = t2 & 7;
      const int r = t2 >> 3;
      const int ygl = y0 - PAD + r;
      const int xb = x0 - PAD + pxq * 4;
      float4 va = make_float4(0.f, 0.f, 0.f, 0.f), vb = va;
      if (ygl >= 0 && ygl < H_ && xb >= 0 && xb <= W_ - 4) {
        const float* p = f2b + ((size_t)(c0 + 2 * cp) * H_ + ygl) * W_ + xb;
        va = *(const float4*)p;
        vb = *(const float4*)(p + HW);
      }
      unsigned* d = &f2s[(r * F2PX + pxq * 4) * PXS + cp];
      d[0 * PXS] = packbf2(va.x, vb.x);
      d[1 * PXS] = packbf2(va.y, vb.y);
      d[2 * PXS] = packbf2(va.z, vb.z);
      d[3 * PXS] = packbf2(va.w, vb.w);
    }
    {
      const int cp = t & 15;
      const int t2 = t >> 4;
      const int pxq = t2 & 3;
      const int r = t2 >> 2;
      const float* p =
          f1b + ((size_t)(c0 + 2 * cp) * H_ + (y0 + r)) * W_ + x0 + pxq * 4;
      const float4 va = *(const float4*)p;
      const float4 vb = *(const float4*)(p + HW);
      unsigned* d = &f1s[(r * XB + pxq * 4) * PXS + cp];
      d[0 * PXS] = packbf2(va.x, vb.x);
      d[1 * PXS] = packbf2(va.y, vb.y);
      d[2 * PXS] = packbf2(va.z, vb.z);
      d[3 * PXS] = packbf2(va.w, vb.w);
    }
    __syncthreads();

    const short8 af = __builtin_bit_cast(
        short8, *(const uint4*)&f1s[(w * XB + v) * PXS + 4 * q]);
#pragma unroll
    for (int dy = 0; dy < SIDE; ++dy) {
      const unsigned* fp = &f2s[((w + dy) * F2PX + v) * PXS + 4 * q];
      const short8 b0 = __builtin_bit_cast(short8, *(const uint4*)fp);
      const short8 b1 =
          __builtin_bit_cast(short8, *(const uint4*)(fp + 16 * PXS));
      acc[dy][0] =
          __builtin_amdgcn_mfma_f32_16x16x32_bf16(af, b0, acc[dy][0], 0, 0, 0);
      acc[dy][1] =
          __builtin_amdgcn_mfma_f32_16x16x32_bf16(af, b1, acc[dy][1], 0, 0, 0);
    }
  }
  const int y = y0 + w;
  float* outb = out + (size_t)b * ND * HW + (size_t)y * W_ + x0;
#pragma unroll
  for (int dy = 0; dy < SIDE; ++dy) {
#pragma unroll
    for (int r = 0; r < 4; ++r) {
      const int m = q * 4 + r;
      const int dx0 = v - m;
      if (dx0 >= 0 && dx0 <= 8)
        outb[(size_t)(dy * SIDE + dx0) * HW + m] = acc[dy][0][r];
      const int dx1 = v - m + 16;
      if (dx1 <= 8)
        outb[(size_t)(dy * SIDE + dx1) * HW + m] = acc[dy][1][r];
    }
  }
}

extern "C" void kernel_launch(void* const* d_in, const int* in_sizes, int n_in,
                              void* d_out, int out_size, void* d_ws,
                              size_t ws_size, hipStream_t stream) {
  (void)in_sizes; (void)n_in; (void)out_size;
  const float* f1 = (const float*)d_in[0];
  const float* f2 = (const float*)d_in[1];
  float* out = (float*)d_out;
  if (ws_size >= WS_BYTES) {
    uint4* w2 = (uint4*)d_ws;
    cvt_f2<<<dim3((unsigned)(NW2 / 512)), 256, 0, stream>>>(f2, w2);
    corr_mfma4<<<dim3(2048), 256, 0, stream>>>(f1, w2, out);
  } else {
    corr_fb<<<dim3(512), 512, 0, stream>>>(f1, f2, out);
  }
}

// Round 8
// 179.449 us; speedup vs baseline: 1.0995x; 1.0776x over previous
//
#include <hip/hip_runtime.h>

// Correlation layer, two-pass banded-MFMA with LDS-DMA pipeline (gfx950).
// out[b, dy*9+dx, y, x] = sum_c f1[b,c,y,x] * f2[b,c,y+dy-4,x+dx-4]
//
// R18 = R13 (best, 52.5us, loop untouched) + LDS-transpose epilogue.
// Theory: the one structure never varied across R9-R16 is the epilogue --
// 72 banded conditional scalar stores/lane scattering ~36 4B segments per
// instr across 9 dx-planes => ~10.6M L2 write transactions in a serial
// burst (~15-20us) + 47% HBM write amplification (R13 WRITE 31MB for a
// 21.2MB output). Fix: after the last chunk, dump acc into the freed 64KB
// staging LDS as eps[dy][dx][y][x] (each cell exactly one writer: x=m,
// tile picked by m+dx<16), barrier, then 512 threads cooperatively store
// 2592 float4 slots -- 64B dense segments, full lanes, 32x fewer write
// transactions; neighboring xg blocks merge 64B halves into full L2 lines.
//
// R13 loop kept verbatim (proven): per-chunk {pack -> vmcnt(4) -> s_barrier
// -> f1(ch+1) -> MFMA -> s_barrier -> stage(ch+2)}; per-wave FIFO
// [S(ch):4, f1(ch):8, S(ch+1):4], counted vmcnt never 0 mid-loop; XOR
// swizzle both-sides (verified 0 bank conflicts); b=id&7 XCD pin; 512
// blocks x 512 threads; fragment-ready w2 (42.5MB ws); float2 cvt (R14).

namespace {
constexpr int B_ = 8, C_ = 256, H_ = 64, W_ = 128;
constexpr int SIDE = 9, ND = 81, PAD = 4;
constexpr int HW = H_ * W_;
constexpr int KC = 32, NCH = C_ / KC;       // 8 chunks of 32 channels
constexpr int YB = 8, RWS = YB + 2 * PAD;   // 16 staged f2 rows
constexpr int XB = 16;
constexpr int NQ = 4;                       // channel-octs per chunk
constexpr int YP_ = H_ + 2 * PAD;           // 72
constexpr int XP_ = 144;                    // padded x (x+4)
constexpr size_t ROWU = (size_t)NQ * XP_;   // 576 uint4 per (b,cs,yp)
constexpr size_t PERB = (size_t)NCH * YP_ * ROWU;  // 331,776
constexpr size_t NW2 = (size_t)B_ * PERB;          // 2,654,208 uint4
constexpr size_t WS_BYTES = NW2 * 16;              // 42.5 MB
constexpr int TILE_U4 = RWS * NQ * 32;             // 2048 uint4 = 32 KB
constexpr int EPS_SLOTS = ND * YB * XB / 4;        // 2592 float4 slots
}

typedef __attribute__((ext_vector_type(8))) short short8;
typedef __attribute__((ext_vector_type(4))) float float4v;
typedef __attribute__((address_space(1))) void gvoid;
typedef __attribute__((address_space(3))) void svoid;

__device__ __forceinline__ unsigned bf16rne(float f) {
  unsigned u = __float_as_uint(f);
  return (u + 0x7fffu + ((u >> 16) & 1u)) >> 16;
}
__device__ __forceinline__ unsigned packbf2(float lo, float hi) {
  return bf16rne(lo) | (bf16rne(hi) << 16);
}

// ------- pass 1: f2 fp32 -> fragment-ready bf16 w2, XCD-swizzled -------
// Each thread produces TWO consecutive uint4 (x pair) via float2 loads.
__global__ __launch_bounds__(256)
void cvt_f2(const float* __restrict__ f2, uint4* __restrict__ w2) {
  const int id = blockIdx.x;
  const int b = id & 7;                              // XCD pin
  const int e2 = (id >> 3) * 256 + (int)threadIdx.x; // pair idx
  const int xp2 = e2 % (XP_ / 2);
  int r = e2 / (XP_ / 2);
  const int q = r & 3;
  r >>= 2;
  const int yp = r % YP_;
  const int cs = r / YP_;
  const int xp = 2 * xp2;
  const int yg = yp - PAD, xg = xp - PAD;            // xg even
  uint4 o0 = {0u, 0u, 0u, 0u}, o1 = o0;
  if (yg >= 0 && yg < H_ && xg >= 0 && xg <= W_ - 2) {
    const float* s =
        f2 + ((size_t)(b * C_ + cs * KC + q * 8) * H_ + yg) * W_ + xg;
    const float2 v0 = *(const float2*)(s + 0 * HW);
    const float2 v1 = *(const float2*)(s + 1 * HW);
    const float2 v2 = *(const float2*)(s + 2 * HW);
    const float2 v3 = *(const float2*)(s + 3 * HW);
    const float2 v4 = *(const float2*)(s + 4 * HW);
    const float2 v5 = *(const float2*)(s + 5 * HW);
    const float2 v6 = *(const float2*)(s + 6 * HW);
    const float2 v7 = *(const float2*)(s + 7 * HW);
    o0.x = packbf2(v0.x, v1.x);  o1.x = packbf2(v0.y, v1.y);
    o0.y = packbf2(v2.x, v3.x);  o1.y = packbf2(v2.y, v3.y);
    o0.z = packbf2(v4.x, v5.x);  o1.z = packbf2(v4.y, v5.y);
    o0.w = packbf2(v6.x, v7.x);  o1.w = packbf2(v6.y, v7.y);
  }
  const size_t e = (((size_t)(cs * YP_ + yp) * NQ + q) * XP_) + xp;
  uint4* d = w2 + (size_t)b * PERB + e;
  d[0] = o0;
  d[1] = o1;
}

// ------- pass 2: banded MFMA, LDS-DMA double-buffered chunk pipeline -------
__global__ __launch_bounds__(512, 4)
void corr_mfma2(const float* __restrict__ f1, const uint4* __restrict__ w2,
                float* __restrict__ out) {
  __shared__ uint4 f2s[2 * TILE_U4];             // 64 KB, two 32 KB buffers

  const int id = blockIdx.x;
  const int b = id & 7;                          // XCD pin (matches cvt)
  const int k = id >> 3;                         // 0..63
  const int xg = k & 7, yg = k >> 3;             // xg fast: neighbors share rows
  const int x0 = xg * XB, y0 = yg * YB;

  const int t = threadIdx.x, lane = t & 63, w = t >> 6;  // wave -> y row y0+w
  const int v = lane & 15, q = lane >> 4;
  const int sq = q << 1;                         // read-side XOR swizzle
  const int l_hi = lane >> 5;                    // staging lane geometry
  const int l_xq = lane & 31;

  const uint4* w2b = w2 + (size_t)b * PERB;
  const float* f1b = f1 + (size_t)b * C_ * HW;

  auto issue_stage = [&](int ch, int buf) {
    const uint4* wc = w2b + (size_t)ch * ((size_t)YP_ * ROWU);
#pragma unroll
    for (int kk = 0; kk < 4; ++kk) {
      const int r = 2 * w + (kk >> 1);
      const int qp = kk & 1;
      const int qq = 2 * qp + l_hi;
      const int xqs = l_xq ^ (qq << 1);
      const uint4* gp = wc + (size_t)(y0 + r) * ROWU + (size_t)qq * XP_ + x0 + xqs;
      uint4* lp = &f2s[buf * TILE_U4 + (r * NQ + qp * 2) * 32];
      __builtin_amdgcn_global_load_lds((gvoid*)gp, (svoid*)lp, 16, 0, 0);
    }
  };
  auto issue_f1 = [&](int ch, float* p) {
    const float* fp =
        f1b + ((size_t)(ch * KC + q * 8) * H_ + (y0 + w)) * W_ + x0 + v;
#pragma unroll
    for (int j = 0; j < 8; ++j) p[j] = fp[(size_t)j * HW];
  };

  float4v acc[SIDE][2];
#pragma unroll
  for (int i = 0; i < SIDE; ++i) {
    acc[i][0] = (float4v){0.f, 0.f, 0.f, 0.f};
    acc[i][1] = (float4v){0.f, 0.f, 0.f, 0.f};
  }

  float p0[8], p1[8];
  issue_stage(0, 0);
  __builtin_amdgcn_sched_barrier(0);
  issue_f1(0, p0);
  __builtin_amdgcn_sched_barrier(0);
  issue_stage(1, 1);
  __builtin_amdgcn_sched_barrier(0);

#pragma unroll
  for (int ch = 0; ch < NCH; ++ch) {
    float* pc = (ch & 1) ? p1 : p0;              // ch literal under unroll
    uint4 afu;
    afu.x = packbf2(pc[0], pc[1]);
    afu.y = packbf2(pc[2], pc[3]);
    afu.z = packbf2(pc[4], pc[5]);
    afu.w = packbf2(pc[6], pc[7]);
    const short8 af = __builtin_bit_cast(short8, afu);

    // FIFO: [S(ch):4, f1(ch):8, S(ch+1):4]; pack's implicit wait + this
    // vmcnt(4) drain S(ch)+f1(ch); S(ch+1) stays in flight (never 0).
    asm volatile("s_waitcnt vmcnt(4)" ::: "memory");
    __builtin_amdgcn_s_barrier();
    __builtin_amdgcn_sched_barrier(0);

    if (ch + 1 < NCH) issue_f1(ch + 1, (ch & 1) ? p0 : p1);

    const int bo = (ch & 1) * TILE_U4;
#pragma unroll
    for (int dy = 0; dy < SIDE; ++dy) {
      const uint4* base = &f2s[bo + ((w + dy) * NQ + q) * 32];
      const short8 b0 = __builtin_bit_cast(short8, base[v ^ sq]);
      const short8 b1 = __builtin_bit_cast(short8, base[(v + 16) ^ sq]);
      acc[dy][0] =
          __builtin_amdgcn_mfma_f32_16x16x32_bf16(af, b0, acc[dy][0], 0, 0, 0);
      acc[dy][1] =
          __builtin_amdgcn_mfma_f32_16x16x32_bf16(af, b1, acc[dy][1], 0, 0, 0);
    }
    __builtin_amdgcn_sched_barrier(0);
    __builtin_amdgcn_s_barrier();                // all readers of buf done
    __builtin_amdgcn_sched_barrier(0);
    if (ch + 2 < NCH) issue_stage(ch + 2, ch & 1);  // overwrite after barrier
  }

  // ---- epilogue: LDS transpose -> coalesced stores ----
  // acc element (dy, tile, r) of lane (v,q): x = m = q*4+r, dx = v-m (tile0,
  // in [0,8]) or v-m+16 (tile1, in [1,8]). For each (dy,dx,x): exactly one
  // writer (v = m+dx if <16 else m+dx-16). eps[dy][dx][y][x], 41.5 KB in
  // the freed staging LDS.
  __builtin_amdgcn_s_barrier();                  // last chunk's ds_reads done
  float* eps = (float*)f2s;
#pragma unroll
  for (int dy = 0; dy < SIDE; ++dy) {
#pragma unroll
    for (int r = 0; r < 4; ++r) {
      const int m = q * 4 + r;
      const int dx0 = v - m;
      if (dx0 >= 0 && dx0 <= 8)
        eps[((dy * SIDE + dx0) * YB + w) * XB + m] = acc[dy][0][r];
      const int dx1 = dx0 + 16;
      if (dx1 <= 8)
        eps[((dy * SIDE + dx1) * YB + w) * XB + m] = acc[dy][1][r];
    }
  }
  __builtin_amdgcn_s_barrier();
  // 81 planes x 8 rows x 16 cols = 2592 float4 slots; slot s: plane s>>5,
  // row (s&31)>>2, xquad s&3. 64B dense segments, full 64-lane stores.
  float* outp = out + (size_t)b * ND * HW;
  for (int s = t; s < EPS_SLOTS; s += 512) {
    const int p = s >> 5;
    const int yy = (s & 31) >> 2;
    const int xq = s & 3;
    const float4 val = *(const float4*)&eps[s * 4];
    *(float4*)&outp[((size_t)p * H_ + y0 + yy) * W_ + x0 + xq * 4] = val;
  }
}

// ---------------- fallback (R10 fused kernel, proven) if ws too small ------
namespace fb {
constexpr int PXS = 20, F2PX = 32, F2U = 16 * (F2PX / 4) * 16;
}

__global__ __launch_bounds__(512, 4)
void corr_fb(const float* __restrict__ f1, const float* __restrict__ f2,
             float* __restrict__ out) {
  using namespace fb;
  __shared__ __align__(16) unsigned f2s[RWS * F2PX * PXS];
  __shared__ __align__(16) unsigned f1s[YB * XB * PXS];

  const int id = blockIdx.x;
  const int b = id & 7;
  const int k = id >> 3;
  const int xg = k & 7, yg = k >> 3;
  const int x0 = xg * XB, y0 = yg * YB;
  const int t = threadIdx.x, lane = t & 63, w = t >> 6;
  const int v = lane & 15, q = lane >> 4;

  float4v acc[SIDE][2];
#pragma unroll
  for (int i = 0; i < SIDE; ++i) {
    acc[i][0] = (float4v){0.f, 0.f, 0.f, 0.f};
    acc[i][1] = (float4v){0.f, 0.f, 0.f, 0.f};
  }
  const float* __restrict__ f1b = f1 + (size_t)b * C_ * HW;
  const float* __restrict__ f2b = f2 + (size_t)b * C_ * HW;

  for (int ch = 0; ch < NCH; ++ch) {
    const int c0 = ch * KC;
    if (ch) __syncthreads();
#pragma unroll
    for (int u0 = 0; u0 < F2U; u0 += 512) {
      const int u = u0 + t;
      const int cp = u & 15;
      const int t2 = u >> 4;
      const int pxq = t2 & 7;
      const int r = t2 >> 3;
      const int ygl = y0 - PAD + r;
      const int xb = x0 - PAD + pxq * 4;
      float4 va = make_float4(0.f, 0.f, 0.f, 0.f), vb = va;
      if (ygl >= 0 && ygl < H_ && xb >= 0 && xb <= W_ - 4) {
        const float* p = f2b + ((size_t)(c0 + 2 * cp) * H_ + ygl) * W_ + xb;
        va = *(const float4*)p;
        vb = *(const float4*)(p + HW);
      }
      unsigned* d = &f2s[(r * F2PX + pxq * 4) * PXS + cp];
      d[0 * PXS] = packbf2(va.x, vb.x);
      d[1 * PXS] = packbf2(va.y, vb.y);
      d[2 * PXS] = packbf2(va.z, vb.z);
      d[3 * PXS] = packbf2(va.w, vb.w);
    }
    {
      const int cp = t & 15;
      const int t2 = t >> 4;
      const int pxq = t2 & 3;
      const int r = t2 >> 2;
      const float* p =
          f1b + ((size_t)(c0 + 2 * cp) * H_ + (y0 + r)) * W_ + x0 + pxq * 4;
      const float4 va = *(const float4*)p;
      const float4 vb = *(const float4*)(p + HW);
      unsigned* d = &f1s[(r * XB + pxq * 4) * PXS + cp];
      d[0 * PXS] = packbf2(va.x, vb.x);
      d[1 * PXS] = packbf2(va.y, vb.y);
      d[2 * PXS] = packbf2(va.z, vb.z);
      d[3 * PXS] = packbf2(va.w, vb.w);
    }
    __syncthreads();

    const short8 af = __builtin_bit_cast(
        short8, *(const uint4*)&f1s[(w * XB + v) * PXS + 4 * q]);
#pragma unroll
    for (int dy = 0; dy < SIDE; ++dy) {
      const unsigned* fp = &f2s[((w + dy) * F2PX + v) * PXS + 4 * q];
      const short8 b0 = __builtin_bit_cast(short8, *(const uint4*)fp);
      const short8 b1 =
          __builtin_bit_cast(short8, *(const uint4*)(fp + 16 * PXS));
      acc[dy][0] =
          __builtin_amdgcn_mfma_f32_16x16x32_bf16(af, b0, acc[dy][0], 0, 0, 0);
      acc[dy][1] =
          __builtin_amdgcn_mfma_f32_16x16x32_bf16(af, b1, acc[dy][1], 0, 0, 0);
    }
  }
  const int y = y0 + w;
  float* outb = out + (size_t)b * ND * HW + (size_t)y * W_ + x0;
#pragma unroll
  for (int dy = 0; dy < SIDE; ++dy) {
#pragma unroll
    for (int r = 0; r < 4; ++r) {
      const int m = q * 4 + r;
      const int dx0 = v - m;
      if (dx0 >= 0 && dx0 <= 8)
        outb[(size_t)(dy * SIDE + dx0) * HW + m] = acc[dy][0][r];
      const int dx1 = v - m + 16;
      if (dx1 <= 8)
        outb[(size_t)(dy * SIDE + dx1) * HW + m] = acc[dy][1][r];
    }
  }
}

extern "C" void kernel_launch(void* const* d_in, const int* in_sizes, int n_in,
                              void* d_out, int out_size, void* d_ws,
                              size_t ws_size, hipStream_t stream) {
  (void)in_sizes; (void)n_in; (void)out_size;
  const float* f1 = (const float*)d_in[0];
  const float* f2 = (const float*)d_in[1];
  float* out = (float*)d_out;
  if (ws_size >= WS_BYTES) {
    uint4* w2 = (uint4*)d_ws;
    cvt_f2<<<dim3((unsigned)(NW2 / 512)), 256, 0, stream>>>(f2, w2);
    corr_mfma2<<<dim3(512), 512, 0, stream>>>(f1, w2, out);
  } else {
    corr_fb<<<dim3(512), 512, 0, stream>>>(f1, f2, out);
  }
}

// Round 9
// 175.789 us; speedup vs baseline: 1.1224x; 1.0208x over previous
//
#include <hip/hip_runtime.h>

// Correlation layer, two-pass banded-MFMA with LDS-DMA pipeline (gfx950).
// out[b, dy*9+dx, y, x] = sum_c f1[b,c,y,x] * f2[b,c,y+dy-4,x+dx-4]
//
// R19: YB=16, 2 y-rows per wave, 256 blocks (ONE round, exactly 1/CU).
// Ledger R13-R18: 47-53us band survived pipeline depth, barrier count,
// buffering, occupancy, epilogue format. Invariant: per-CU work split into
// 16 barrier-coupled block-instances (2 rounds x 8 chunks) with ~3kcy
// fixed latency each. R19 makes every per-CU cost strictly smaller:
//  - barriers per unit work halved (8 chunks for 2x output);
//  - LDS reads/MFMA cut 1.8x: wave's rows 2w+dy, 2w+1+dy share B-rows via
//    rolling bA<-bB register reuse (10 row-reads -> 36 MFMA per chunk);
//  - DMA -25% (24 staged rows per 16 outputs vs 16 per 8, halo amortized);
//  - staged rows y0..y0+23 <= 71: OOB clamp gone.
// acc 144 AGPR + ~70 VGPR -> __launch_bounds__(512,2) (256-reg cap).
// LDS: 2 x 48KB staging + 81KB eps (reuse) <= 160KB.
// Kept verbatim (proven): chunk skeleton {pack -> vmcnt(6) -> s_barrier ->
// f1(ch+1) -> MFMA -> s_barrier -> stage(ch+2)}, counted vmcnt never 0
// mid-loop, XOR swizzle both-sides (0 conflicts), b=id&7 XCD pin,
// fragment-ready w2 (42.5MB ws), float2 cvt (R14), R18 LDS-transpose
// epilogue with dense float4 stores.

namespace {
constexpr int B_ = 8, C_ = 256, H_ = 64, W_ = 128;
constexpr int SIDE = 9, ND = 81, PAD = 4;
constexpr int HW = H_ * W_;
constexpr int KC = 32, NCH = C_ / KC;       // 8 chunks of 32 channels
constexpr int YB = 16, RWS = YB + 2 * PAD;  // 24 staged f2 rows
constexpr int XB = 16;
constexpr int NQ = 4;                       // channel-octs per chunk
constexpr int YP_ = H_ + 2 * PAD;           // 72
constexpr int XP_ = 144;                    // padded x (x+4)
constexpr size_t ROWU = (size_t)NQ * XP_;   // 576 uint4 per (b,cs,yp)
constexpr size_t PERB = (size_t)NCH * YP_ * ROWU;  // 331,776
constexpr size_t NW2 = (size_t)B_ * PERB;          // 2,654,208 uint4
constexpr size_t WS_BYTES = NW2 * 16;              // 42.5 MB
constexpr int TILE_U4 = RWS * NQ * 32;             // 3072 uint4 = 48 KB
constexpr int EPS_SLOTS = ND * YB * XB / 4;        // 5184 float4 slots
}

typedef __attribute__((ext_vector_type(8))) short short8;
typedef __attribute__((ext_vector_type(4))) float float4v;
typedef __attribute__((address_space(1))) void gvoid;
typedef __attribute__((address_space(3))) void svoid;

__device__ __forceinline__ unsigned bf16rne(float f) {
  unsigned u = __float_as_uint(f);
  return (u + 0x7fffu + ((u >> 16) & 1u)) >> 16;
}
__device__ __forceinline__ unsigned packbf2(float lo, float hi) {
  return bf16rne(lo) | (bf16rne(hi) << 16);
}

// ------- pass 1: f2 fp32 -> fragment-ready bf16 w2, XCD-swizzled -------
__global__ __launch_bounds__(256)
void cvt_f2(const float* __restrict__ f2, uint4* __restrict__ w2) {
  const int id = blockIdx.x;
  const int b = id & 7;                              // XCD pin
  const int e2 = (id >> 3) * 256 + (int)threadIdx.x; // pair idx
  const int xp2 = e2 % (XP_ / 2);
  int r = e2 / (XP_ / 2);
  const int q = r & 3;
  r >>= 2;
  const int yp = r % YP_;
  const int cs = r / YP_;
  const int xp = 2 * xp2;
  const int yg = yp - PAD, xg = xp - PAD;            // xg even
  uint4 o0 = {0u, 0u, 0u, 0u}, o1 = o0;
  if (yg >= 0 && yg < H_ && xg >= 0 && xg <= W_ - 2) {
    const float* s =
        f2 + ((size_t)(b * C_ + cs * KC + q * 8) * H_ + yg) * W_ + xg;
    const float2 v0 = *(const float2*)(s + 0 * HW);
    const float2 v1 = *(const float2*)(s + 1 * HW);
    const float2 v2 = *(const float2*)(s + 2 * HW);
    const float2 v3 = *(const float2*)(s + 3 * HW);
    const float2 v4 = *(const float2*)(s + 4 * HW);
    const float2 v5 = *(const float2*)(s + 5 * HW);
    const float2 v6 = *(const float2*)(s + 6 * HW);
    const float2 v7 = *(const float2*)(s + 7 * HW);
    o0.x = packbf2(v0.x, v1.x);  o1.x = packbf2(v0.y, v1.y);
    o0.y = packbf2(v2.x, v3.x);  o1.y = packbf2(v2.y, v3.y);
    o0.z = packbf2(v4.x, v5.x);  o1.z = packbf2(v4.y, v5.y);
    o0.w = packbf2(v6.x, v7.x);  o1.w = packbf2(v6.y, v7.y);
  }
  const size_t e = (((size_t)(cs * YP_ + yp) * NQ + q) * XP_) + xp;
  uint4* d = w2 + (size_t)b * PERB + e;
  d[0] = o0;
  d[1] = o1;
}

// ------- pass 2: banded MFMA, 2 rows/wave, 1 block/CU, single round -------
__global__ __launch_bounds__(512, 2)
void corr_mfma5(const float* __restrict__ f1, const uint4* __restrict__ w2,
                float* __restrict__ out) {
  __shared__ uint4 f2s[2 * TILE_U4];             // 96 KB, two 48 KB buffers

  const int id = blockIdx.x;                     // 0..255
  const int b = id & 7;                          // XCD pin (matches cvt)
  const int k = id >> 3;                         // 0..31
  const int xg = k & 7, yg = k >> 3;             // yg 0..3
  const int x0 = xg * XB, y0 = yg * YB;

  const int t = threadIdx.x, lane = t & 63, w = t >> 6;  // rows y0+2w, +2w+1
  const int v = lane & 15, q = lane >> 4;
  const int sq = q << 1;                         // read-side XOR swizzle
  const int l_hi = lane >> 5;                    // staging lane geometry
  const int l_xq = lane & 31;

  const uint4* w2b = w2 + (size_t)b * PERB;
  const float* f1b = f1 + (size_t)b * C_ * HW;

  // 6 global_load_lds per wave per chunk: g=w*6+kk -> row r=g>>1 (0..23),
  // oct-pair qp=g&1; lane -> oct qq=2qp+(lane>>5), slot xq=lane&31, source
  // col x0+(xq^(qq<<1)) (pre-swizzled global, linear LDS dest).
  auto issue_stage = [&](int ch, int buf) {
    const uint4* wc = w2b + (size_t)ch * ((size_t)YP_ * ROWU);
#pragma unroll
    for (int kk = 0; kk < 6; ++kk) {
      const int g = w * 6 + kk;
      const int r = g >> 1, qp = g & 1;
      const int qq = 2 * qp + l_hi;
      const int xqs = l_xq ^ (qq << 1);
      const uint4* gp =
          wc + (size_t)(y0 + r) * ROWU + (size_t)qq * XP_ + x0 + xqs;
      uint4* lp = &f2s[buf * TILE_U4 + (r * NQ + qp * 2) * 32];
      __builtin_amdgcn_global_load_lds((gvoid*)gp, (svoid*)lp, 16, 0, 0);
    }
  };
  // f1 for both rows: 16 scalar loads into p[0..7] (row 2w), p[8..15].
  auto issue_f1 = [&](int ch, float* p) {
    const float* fp =
        f1b + ((size_t)(ch * KC + q * 8) * H_ + (y0 + 2 * w)) * W_ + x0 + v;
#pragma unroll
    for (int j = 0; j < 8; ++j) p[j] = fp[(size_t)j * HW];
#pragma unroll
    for (int j = 0; j < 8; ++j) p[8 + j] = fp[(size_t)j * HW + W_];
  };

  float4v acc[2][SIDE][2];
#pragma unroll
  for (int i = 0; i < 2; ++i)
#pragma unroll
    for (int d = 0; d < SIDE; ++d) {
      acc[i][d][0] = (float4v){0.f, 0.f, 0.f, 0.f};
      acc[i][d][1] = (float4v){0.f, 0.f, 0.f, 0.f};
    }

  float p0[16], p1[16];
  issue_stage(0, 0);
  __builtin_amdgcn_sched_barrier(0);
  issue_f1(0, p0);
  __builtin_amdgcn_sched_barrier(0);
  issue_stage(1, 1);
  __builtin_amdgcn_sched_barrier(0);

#pragma unroll
  for (int ch = 0; ch < NCH; ++ch) {
    float* pc = (ch & 1) ? p1 : p0;
    uint4 a0u, a1u;
    a0u.x = packbf2(pc[0], pc[1]);
    a0u.y = packbf2(pc[2], pc[3]);
    a0u.z = packbf2(pc[4], pc[5]);
    a0u.w = packbf2(pc[6], pc[7]);
    a1u.x = packbf2(pc[8], pc[9]);
    a1u.y = packbf2(pc[10], pc[11]);
    a1u.z = packbf2(pc[12], pc[13]);
    a1u.w = packbf2(pc[14], pc[15]);
    const short8 af0 = __builtin_bit_cast(short8, a0u);
    const short8 af1 = __builtin_bit_cast(short8, a1u);

    // FIFO: [S(ch):6, f1(ch):16, S(ch+1):6]; pack's implicit waits + this
    // vmcnt(6) drain S(ch)+f1(ch); S(ch+1) stays in flight (never 0).
    asm volatile("s_waitcnt vmcnt(6)" ::: "memory");
    __builtin_amdgcn_s_barrier();
    __builtin_amdgcn_sched_barrier(0);

    if (ch + 1 < NCH) issue_f1(ch + 1, (ch & 1) ? p0 : p1);

    const int bo = (ch & 1) * TILE_U4;
    // Rolling B-row reuse: bA = row 2w+dy, bB = row 2w+1+dy. Per dy>0 only
    // one new row is read (2 b128); 20 reads feed 36 MFMA.
    uint4 bA0, bA1, bB0, bB1;
    {
      const uint4* ra = &f2s[bo + ((2 * w) * NQ + q) * 32];
      bA0 = ra[v ^ sq];
      bA1 = ra[(v + 16) ^ sq];
      const uint4* rb = &f2s[bo + ((2 * w + 1) * NQ + q) * 32];
      bB0 = rb[v ^ sq];
      bB1 = rb[(v + 16) ^ sq];
    }
#pragma unroll
    for (int dy = 0; dy < SIDE; ++dy) {
      if (dy > 0) {
        bA0 = bB0;
        bA1 = bB1;
        const uint4* rb = &f2s[bo + ((2 * w + 1 + dy) * NQ + q) * 32];
        bB0 = rb[v ^ sq];
        bB1 = rb[(v + 16) ^ sq];
      }
      acc[0][dy][0] = __builtin_amdgcn_mfma_f32_16x16x32_bf16(
          af0, __builtin_bit_cast(short8, bA0), acc[0][dy][0], 0, 0, 0);
      acc[0][dy][1] = __builtin_amdgcn_mfma_f32_16x16x32_bf16(
          af0, __builtin_bit_cast(short8, bA1), acc[0][dy][1], 0, 0, 0);
      acc[1][dy][0] = __builtin_amdgcn_mfma_f32_16x16x32_bf16(
          af1, __builtin_bit_cast(short8, bB0), acc[1][dy][0], 0, 0, 0);
      acc[1][dy][1] = __builtin_amdgcn_mfma_f32_16x16x32_bf16(
          af1, __builtin_bit_cast(short8, bB1), acc[1][dy][1], 0, 0, 0);
    }
    __builtin_amdgcn_sched_barrier(0);
    __builtin_amdgcn_s_barrier();                // all readers of buf done
    __builtin_amdgcn_sched_barrier(0);
    if (ch + 2 < NCH) issue_stage(ch + 2, ch & 1);  // overwrite after barrier
  }

  // ---- epilogue: LDS transpose -> coalesced stores (R18-proven) ----
  // acc[i][dy][tile][r], lane (v,q): x = m = q*4+r, y-row = 2w+i,
  // dx = v-m (tile0, [0,8]) or v-m+16 (tile1, [1,8]). One writer per cell.
  __builtin_amdgcn_s_barrier();                  // last chunk consumed
  float* eps = (float*)f2s;                      // 81 KB of the 96 KB
#pragma unroll
  for (int i = 0; i < 2; ++i) {
#pragma unroll
    for (int dy = 0; dy < SIDE; ++dy) {
#pragma unroll
      for (int r = 0; r < 4; ++r) {
        const int m = q * 4 + r;
        const int dx0 = v - m;
        if (dx0 >= 0 && dx0 <= 8)
          eps[((dy * SIDE + dx0) * YB + 2 * w + i) * XB + m] = acc[i][dy][0][r];
        const int dx1 = dx0 + 16;
        if (dx1 <= 8)
          eps[((dy * SIDE + dx1) * YB + 2 * w + i) * XB + m] = acc[i][dy][1][r];
      }
    }
  }
  __builtin_amdgcn_s_barrier();
  // 81 planes x 16 rows x 16 cols = 5184 float4 slots; slot s: plane s>>6,
  // row (s&63)>>2, xquad s&3. 64B dense segments, full 64-lane stores.
  float* outp = out + (size_t)b * ND * HW;
  for (int s = t; s < EPS_SLOTS; s += 512) {
    const int p = s >> 6;
    const int yy = (s & 63) >> 2;
    const int xq = s & 3;
    const float4 val = *(const float4*)&eps[s * 4];
    *(float4*)&outp[((size_t)p * H_ + y0 + yy) * W_ + x0 + xq * 4] = val;
  }
}

// ---------------- fallback (R10 fused kernel, proven) if ws too small ------
namespace fb {
constexpr int PXS = 20, F2PX = 32, RWSf = 16, YBf = 8;
constexpr int F2U = RWSf * (F2PX / 4) * 16;
}

__global__ __launch_bounds__(512, 4)
void corr_fb(const float* __restrict__ f1, const float* __restrict__ f2,
             float* __restrict__ out) {
  using namespace fb;
  __shared__ __align__(16) unsigned f2s[RWSf * F2PX * PXS];
  __shared__ __align__(16) unsigned f1s[YBf * XB * PXS];

  const int id = blockIdx.x;
  const int b = id & 7;
  const int k = id >> 3;
  const int xg = k & 7, yg = k >> 3;
  const int x0 = xg * XB, y0 = yg * YBf;
  const int t = threadIdx.x, lane = t & 63, w = t >> 6;
  const int v = lane & 15, q = lane >> 4;

  float4v acc[SIDE][2];
#pragma unroll
  for (int i = 0; i < SIDE; ++i) {
    acc[i][0] = (float4v){0.f, 0.f, 0.f, 0.f};
    acc[i][1] = (float4v){0.f, 0.f, 0.f, 0.f};
  }
  const float* __restrict__ f1b = f1 + (size_t)b * C_ * HW;
  const float* __restrict__ f2b = f2 + (size_t)b * C_ * HW;

  for (int ch = 0; ch < NCH; ++ch) {
    const int c0 = ch * KC;
    if (ch) __syncthreads();
#pragma unroll
    for (int u0 = 0; u0 < F2U; u0 += 512) {
      const int u = u0 + t;
      const int cp = u & 15;
      const int t2 = u >> 4;
      const int pxq = t2 & 7;
      const int r = t2 >> 3;
      const int ygl = y0 - PAD + r;
      const int xb = x0 - PAD + pxq * 4;
      float4 va = make_float4(0.f, 0.f, 0.f, 0.f), vb = va;
      if (ygl >= 0 && ygl < H_ && xb >= 0 && xb <= W_ - 4) {
        const float* p = f2b + ((size_t)(c0 + 2 * cp) * H_ + ygl) * W_ + xb;
        va = *(const float4*)p;
        vb = *(const float4*)(p + HW);
      }
      unsigned* d = &f2s[(r * F2PX + pxq * 4) * PXS + cp];
      d[0 * PXS] = packbf2(va.x, vb.x);
      d[1 * PXS] = packbf2(va.y, vb.y);
      d[2 * PXS] = packbf2(va.z, vb.z);
      d[3 * PXS] = packbf2(va.w, vb.w);
    }
    {
      const int cp = t & 15;
      const int t2 = t >> 4;
      const int pxq = t2 & 3;
      const int r = t2 >> 2;
      const float* p =
          f1b + ((size_t)(c0 + 2 * cp) * H_ + (y0 + r)) * W_ + x0 + pxq * 4;
      const float4 va = *(const float4*)p;
      const float4 vb = *(const float4*)(p + HW);
      unsigned* d = &f1s[(r * XB + pxq * 4) * PXS + cp];
      d[0 * PXS] = packbf2(va.x, vb.x);
      d[1 * PXS] = packbf2(va.y, vb.y);
      d[2 * PXS] = packbf2(va.z, vb.z);
      d[3 * PXS] = packbf2(va.w, vb.w);
    }
    __syncthreads();

    const short8 af = __builtin_bit_cast(
        short8, *(const uint4*)&f1s[(w * XB + v) * PXS + 4 * q]);
#pragma unroll
    for (int dy = 0; dy < SIDE; ++dy) {
      const unsigned* fp = &f2s[((w + dy) * F2PX + v) * PXS + 4 * q];
      const short8 b0 = __builtin_bit_cast(short8, *(const uint4*)fp);
      const short8 b1 =
          __builtin_bit_cast(short8, *(const uint4*)(fp + 16 * PXS));
      acc[dy][0] =
          __builtin_amdgcn_mfma_f32_16x16x32_bf16(af, b0, acc[dy][0], 0, 0, 0);
      acc[dy][1] =
          __builtin_amdgcn_mfma_f32_16x16x32_bf16(af, b1, acc[dy][1], 0, 0, 0);
    }
  }
  const int y = y0 + w;
  float* outb = out + (size_t)b * ND * HW + (size_t)y * W_ + x0;
#pragma unroll
  for (int dy = 0; dy < SIDE; ++dy) {
#pragma unroll
    for (int r = 0; r < 4; ++r) {
      const int m = q * 4 + r;
      const int dx0 = v - m;
      if (dx0 >= 0 && dx0 <= 8)
        outb[(size_t)(dy * SIDE + dx0) * HW + m] = acc[dy][0][r];
      const int dx1 = v - m + 16;
      if (dx1 <= 8)
        outb[(size_t)(dy * SIDE + dx1) * HW + m] = acc[dy][1][r];
    }
  }
}

extern "C" void kernel_launch(void* const* d_in, const int* in_sizes, int n_in,
                              void* d_out, int out_size, void* d_ws,
                              size_t ws_size, hipStream_t stream) {
  (void)in_sizes; (void)n_in; (void)out_size;
  const float* f1 = (const float*)d_in[0];
  const float* f2 = (const float*)d_in[1];
  float* out = (float*)d_out;
  if (ws_size >= WS_BYTES) {
    uint4* w2 = (uint4*)d_ws;
    cvt_f2<<<dim3((unsigned)(NW2 / 512)), 256, 0, stream>>>(f2, w2);
    corr_mfma5<<<dim3(256), 512, 0, stream>>>(f1, w2, out);
  } else {
    corr_fb<<<dim3(512), 512, 0, stream>>>(f1, f2, out);
  }
}